// Round 11
// baseline (840.209 us; speedup 1.0000x reference)
//
#include <hip/hip_runtime.h>
#include <hip/hip_bf16.h>
#include <math.h>

#define NN 40000
#define EE 320000
#define NT 3
#define LL 3
#define DD 128
#define HID 256
#define NH 4
#define CC 64
#define NP 768   // NT*HID: batched projection width
#define LGRID 2048  // layer_k persistent blocks (8192 waves)

typedef __attribute__((ext_vector_type(8))) short short8;
typedef __attribute__((ext_vector_type(4))) float f32x4;

__device__ __forceinline__ float gelu_f(float x) {
    return 0.5f * x * (1.0f + erff(x * 0.70710678118654752440f));
}
__device__ __forceinline__ float lrelu_f(float x) {
    return x > 0.0f ? x : 0.2f * x;
}
__device__ __forceinline__ float bf2f(unsigned short u) {
    unsigned int x = ((unsigned int)u) << 16;
    float f;
    __builtin_memcpy(&f, &x, 4);
    return f;
}
__device__ __forceinline__ unsigned short f2bf(float f) {
    __hip_bfloat16 h = __float2bfloat16(f);
    unsigned short u;
    __builtin_memcpy(&u, &h, 2);
    return u;
}
__device__ __forceinline__ void gload16(const void* g, void* l) {
    __builtin_amdgcn_global_load_lds(
        (const __attribute__((address_space(1))) unsigned int*)g,
        (__attribute__((address_space(3))) unsigned int*)l, 16, 0, 0);
}

// ---------------- weight transpose + bf16 convert: W[m][K][N] -> Wt[m][N][K] ----------------
__global__ void wconv_k(const float* __restrict__ W, unsigned short* __restrict__ Wt,
                        int nmat, int K, int N) {
    int idx = blockIdx.x * 256 + threadIdx.x;
    int tot = nmat * K * N;
    if (idx >= tot) return;
    int m = idx / (K * N);
    int rem = idx - m * (K * N);
    int k = rem / N;
    int n = rem - k * N;
    Wt[(size_t)m * K * N + (size_t)n * K + k] = f2bf(W[idx]);
}

// ---------------- x fp32 -> bf16 ----------------
__global__ void xconv_k(const float* __restrict__ x, unsigned short* __restrict__ xb) {
    int idx = blockIdx.x * 256 + threadIdx.x;
    if (idx >= NN * DD / 4) return;
    float4 v = *reinterpret_cast<const float4*>(&x[(size_t)idx * 4]);
    ushort4 o;
    o.x = f2bf(v.x); o.y = f2bf(v.y); o.z = f2bf(v.z); o.w = f2bf(v.w);
    *reinterpret_cast<ushort4*>(&xb[(size_t)idx * 4]) = o;
}

// ---------------- MFMA bf16 GEMM: C[M][N] = A[M][K] @ Bt[N][K]^T (+bias) ----------------
// XCD-chunked bijective block swizzle. Optional fused attention-score epilogue:
// when ssp!=null, each warp's 64-col span is exactly one head's channels, so
// score[row][t][h] = sum_c acc[row][c]*a[c] via in-warp 16-lane reduction (fp32 acc,
// pre-bf16-rounding; a pre-scaled by log2e).
__global__ __launch_bounds__(256) void gemm_mfma_k(const unsigned short* __restrict__ A,
                                                   const unsigned short* __restrict__ Bt,
                                                   const float* __restrict__ bias,
                                                   float* __restrict__ Cf,
                                                   unsigned short* __restrict__ Cb,
                                                   const float* __restrict__ as_t, // [NT][NH][CC]
                                                   const float* __restrict__ ad_t,
                                                   float* __restrict__ ssp,        // [NT][NN][NH]
                                                   float* __restrict__ sdp,
                                                   int M, int K, int N) {
    __shared__ __align__(16) short As[128 * 32];
    __shared__ __align__(16) short Bs[128 * 32];
    int gdx = gridDim.x;
    int nwg = gdx * gridDim.y;
    int f = blockIdx.y * gdx + blockIdx.x;
    int q8 = nwg >> 3, r8 = nwg & 7;
    int xcd = f & 7, idx8 = f >> 3;
    int nf = (xcd < r8 ? xcd * (q8 + 1) : r8 * (q8 + 1) + (xcd - r8) * q8) + idx8;
    int bn = (nf % gdx) * 128;
    int bm = (nf / gdx) * 128;
    int tid = threadIdx.x;
    int lane = tid & 63, w = tid >> 6;
    int wr = w >> 1, wc = w & 1;
    int l16 = lane & 15, kgrp = lane >> 4;
    f32x4 acc[4][4] = {};
    for (int k0 = 0; k0 < K; k0 += 32) {
        #pragma unroll
        for (int i = 0; i < 2; i++) {
            int chunk = (i * 4 + w) * 64 + lane;     // 0..511
            int row = chunk >> 2, kq = chunk & 3;
            int grow = bm + row; if (grow > M - 1) grow = M - 1;
            gload16(A + (size_t)grow * K + k0 + kq * 8, &As[(i * 4 + w) * 512]);
        }
        #pragma unroll
        for (int i = 0; i < 2; i++) {
            int chunk = (i * 4 + w) * 64 + lane;
            int row = chunk >> 2, kq = chunk & 3;
            gload16(Bt + (size_t)(bn + row) * K + k0 + kq * 8, &Bs[(i * 4 + w) * 512]);
        }
        __syncthreads();
        short8 af[4], bf[4];
        #pragma unroll
        for (int mi = 0; mi < 4; mi++) {
            int row = wr * 64 + mi * 16 + l16;
            af[mi] = *reinterpret_cast<const short8*>(&As[row * 32 + kgrp * 8]);
        }
        #pragma unroll
        for (int ni = 0; ni < 4; ni++) {
            int nrow = wc * 64 + ni * 16 + l16;
            bf[ni] = *reinterpret_cast<const short8*>(&Bs[nrow * 32 + kgrp * 8]);
        }
        #pragma unroll
        for (int mi = 0; mi < 4; mi++)
            #pragma unroll
            for (int ni = 0; ni < 4; ni++)
                acc[mi][ni] = __builtin_amdgcn_mfma_f32_16x16x32_bf16(af[mi], bf[ni], acc[mi][ni], 0, 0, 0);
        __syncthreads();
    }
    #pragma unroll
    for (int mi = 0; mi < 4; mi++) {
        #pragma unroll
        for (int r = 0; r < 4; r++) {
            int row = bm + wr * 64 + mi * 16 + kgrp * 4 + r;
            if (row < M) {
                #pragma unroll
                for (int ni = 0; ni < 4; ni++) {
                    int col = bn + wc * 64 + ni * 16 + l16;
                    float v = acc[mi][ni][r] + (bias ? bias[col] : 0.0f);
                    if (Cf) Cf[(size_t)row * N + col] = v;
                    if (Cb) Cb[(size_t)row * N + col] = f2bf(v);
                }
            }
        }
    }
    // ---- fused attention-score epilogue (layer GEMMs only) ----
    if (ssp) {
        const float L2E = 1.4426950408889634f;
        int hg = (bn >> 6) + wc;          // global head index 0..11
        int t = hg >> 2, hh = hg & 3;
        const float* ab = as_t + ((size_t)t * NH + hh) * CC;
        const float* db = ad_t + ((size_t)t * NH + hh) * CC;
        float asv[4], adv[4];
        #pragma unroll
        for (int ni = 0; ni < 4; ni++) {
            int c = ni * 16 + l16;
            asv[ni] = ab[c] * L2E;
            adv[ni] = db[c] * L2E;
        }
        #pragma unroll
        for (int mi = 0; mi < 4; mi++) {
            #pragma unroll
            for (int r = 0; r < 4; r++) {
                float ps = acc[mi][0][r] * asv[0] + acc[mi][1][r] * asv[1]
                         + acc[mi][2][r] * asv[2] + acc[mi][3][r] * asv[3];
                float pd = acc[mi][0][r] * adv[0] + acc[mi][1][r] * adv[1]
                         + acc[mi][2][r] * adv[2] + acc[mi][3][r] * adv[3];
                #pragma unroll
                for (int o = 8; o; o >>= 1) { ps += __shfl_xor(ps, o); pd += __shfl_xor(pd, o); }
                int row = bm + wr * 64 + mi * 16 + kgrp * 4 + r;
                if (l16 == 0 && row < M) {
                    ssp[((size_t)t * NN + row) * NH + hh] = ps;
                    sdp[((size_t)t * NN + row) * NH + hh] = pd;
                }
            }
        }
    }
}

// ---------------- LayerNorm + GELU from bf16 input, one wave per row of 256 ----------------
__global__ __launch_bounds__(256) void ln_gelu_bf_k(const unsigned short* __restrict__ y,
                                                    const float* __restrict__ g,
                                                    const float* __restrict__ b,
                                                    unsigned short* __restrict__ outb) {
    int n = blockIdx.x * 4 + (threadIdx.x >> 6);
    int lane = threadIdx.x & 63;
    ushort4 u = *reinterpret_cast<const ushort4*>(&y[(size_t)n * HID + lane * 4]);
    float v0 = bf2f(u.x), v1 = bf2f(u.y), v2 = bf2f(u.z), v3 = bf2f(u.w);
    float s = v0 + v1 + v2 + v3;
    float q = v0 * v0 + v1 * v1 + v2 * v2 + v3 * v3;
    #pragma unroll
    for (int o = 32; o; o >>= 1) { s += __shfl_xor(s, o); q += __shfl_xor(q, o); }
    float mean = s * (1.0f / HID);
    float var = q * (1.0f / HID) - mean * mean;
    float rs = rsqrtf(var + 1e-5f);
    float4 gv = *reinterpret_cast<const float4*>(&g[lane * 4]);
    float4 bv = *reinterpret_cast<const float4*>(&b[lane * 4]);
    ushort4 ob;
    ob.x = f2bf(gelu_f(gv.x * (v0 - mean) * rs + bv.x));
    ob.y = f2bf(gelu_f(gv.y * (v1 - mean) * rs + bv.y));
    ob.z = f2bf(gelu_f(gv.z * (v2 - mean) * rs + bv.z));
    ob.w = f2bf(gelu_f(gv.w * (v3 - mean) * rs + bv.w));
    *reinterpret_cast<ushort4*>(&outb[(size_t)n * HID + lane * 4]) = ob;
}

// ---------------- CSR build: batched over 3 edge types ----------------
__global__ void hist_k(const int* __restrict__ ei, int* __restrict__ cnt) {
    int gid = blockIdx.x * 256 + threadIdx.x;
    if (gid >= NT * EE) return;
    int t = gid / EE, e = gid - t * EE;
    int dst = ei[(size_t)t * 2 * EE + EE + e];
    atomicAdd(&cnt[t * NN + dst], 1);
}

__global__ __launch_bounds__(256) void scan1_k(const int* __restrict__ cnt, int* __restrict__ bsum, int n) {
    int i = blockIdx.x * 256 + threadIdx.x;
    int v = (i < n) ? cnt[i] : 0;
    #pragma unroll
    for (int o = 32; o; o >>= 1) v += __shfl_xor(v, o);
    __shared__ int s4[4];
    if ((threadIdx.x & 63) == 0) s4[threadIdx.x >> 6] = v;
    __syncthreads();
    if (threadIdx.x == 0) bsum[blockIdx.x] = s4[0] + s4[1] + s4[2] + s4[3];
}

__global__ __launch_bounds__(512) void scan2_k(const int* __restrict__ bsum, int* __restrict__ boff, int nb) {
    __shared__ int sh[512];
    int t = threadIdx.x;
    int v = (t < nb) ? bsum[t] : 0;
    sh[t] = v;
    __syncthreads();
    for (int o = 1; o < 512; o <<= 1) {
        int tv = (t >= o) ? sh[t - o] : 0;
        __syncthreads();
        sh[t] += tv;
        __syncthreads();
    }
    if (t < nb) boff[t] = sh[t] - v;
}

__global__ __launch_bounds__(256) void scan3_k(const int* __restrict__ cnt, const int* __restrict__ boff,
                                               int* __restrict__ roff, int n) {
    int i = blockIdx.x * 256 + threadIdx.x;
    int lane = threadIdx.x & 63, w = threadIdx.x >> 6;
    int v = (i < n) ? cnt[i] : 0;
    int s = v;
    #pragma unroll
    for (int o = 1; o < 64; o <<= 1) {
        int tv = __shfl_up(s, o);
        if (lane >= o) s += tv;
    }
    __shared__ int ws_[4];
    if (lane == 63) ws_[w] = s;
    __syncthreads();
    int add = 0;
    for (int k = 0; k < 4; k++) if (k < w) add += ws_[k];
    int incl = s + add + boff[blockIdx.x];
    if (i < n) roff[i] = incl - v;
    if (i == n - 1) roff[n] = incl;
}

__global__ void scatter_k(const int* __restrict__ ei, const float* __restrict__ ew,
                          const int* __restrict__ roff, int* __restrict__ cur,
                          int* __restrict__ csr_src, float* __restrict__ csr_ew) {
    int gid = blockIdx.x * 256 + threadIdx.x;
    if (gid >= NT * EE) return;
    int t = gid / EE, e = gid - t * EE;
    int src = ei[(size_t)t * 2 * EE + e];
    int dst = ei[(size_t)t * 2 * EE + EE + e];
    int pos = roff[t * NN + dst] + atomicAdd(&cur[t * NN + dst], 1);
    csr_src[pos] = src;
    csr_ew[pos] = ew[gid];
}

// ---------------- edge-weight gate from CSR ----------------
__global__ void ewg_kernel(const int* __restrict__ roff, const float* __restrict__ csr_ew,
                           float* __restrict__ ewg) {
    int n = blockIdx.x * 256 + threadIdx.x;
    if (n >= NN) return;
    float ws = 0.0f;
    int dg = 0;
    for (int t = 0; t < NT; t++) {
        int beg = roff[t * NN + n], end = roff[t * NN + n + 1];
        dg += end - beg;
        for (int e = beg; e < end; e++) ws += csr_ew[e];
    }
    float m = dg > 1 ? (float)dg : 1.0f;
    float z = ws / m;
    ewg[n] = 0.5f + 1.0f / (1.0f + __expf(-z));
}

// ---- fused layer: 3-type GAT agg (no-max softmax via exp2, chunk-4 gathers, 32-bit
//      voffsets) + gate + ewg + residual + LN + GELU. Persistent grid-stride waves.
__global__ __launch_bounds__(256) void layer_k(const unsigned short* __restrict__ xpa, // [NN][768]
                                               const float* __restrict__ ss,
                                               const float* __restrict__ sd,
                                               const int* __restrict__ roff,
                                               const int* __restrict__ rsrc,
                                               const float* __restrict__ gatb,  // [3][256]
                                               const float* __restrict__ liq,
                                               const float* __restrict__ gW,    // [260]
                                               const float* __restrict__ gb,    // [1]
                                               const float* __restrict__ ewg,
                                               const float* __restrict__ lg,
                                               const float* __restrict__ lb,
                                               float* __restrict__ hout,
                                               unsigned short* __restrict__ hb) { // in+out
    int wid = blockIdx.x * 4 + (threadIdx.x >> 6);
    int lane = threadIdx.x & 63;
    int h = lane >> 4;
    const int nw = LGRID * 4;
    const char* xpa_b = (const char*)xpa;
    const char* ss_b = (const char*)ss;
    float4 bb0 = *reinterpret_cast<const float4*>(&gatb[lane * 4]);
    float4 bb1 = *reinterpret_cast<const float4*>(&gatb[HID + lane * 4]);
    float4 bb2 = *reinterpret_cast<const float4*>(&gatb[2 * HID + lane * 4]);
    float bs0 = bb0.x + bb1.x + bb2.x;
    float bs1 = bb0.y + bb1.y + bb2.y;
    float bs2 = bb0.z + bb1.z + bb2.z;
    float bs3 = bb0.w + bb1.w + bb2.w;
    float4 gwv = *reinterpret_cast<const float4*>(&gW[lane * 4]);
    float gwl = (lane < 4) ? gW[HID + lane] : 0.0f;
    float gb0 = gb[0];
    float4 lgv = *reinterpret_cast<const float4*>(&lg[lane * 4]);
    float4 lbv = *reinterpret_cast<const float4*>(&lb[lane * 4]);

    for (int node = wid; node < NN; node += nw) {
        float agg0 = 0, agg1 = 0, agg2 = 0, agg3 = 0;
        #pragma unroll
        for (int t = 0; t < NT; t++) {
            int base = t * NN;
            int beg = roff[base + node], end = roff[base + node + 1];
            if (beg == end) continue;
            float sdh = sd[(size_t)(base + node) * NH + h];
            unsigned int cxp = (unsigned int)(t * 512 + lane * 8);       // byte off in xpa rows
            unsigned int css = (unsigned int)(t * NN * 16 + h * 4);      // byte off in ss
            float den = 0, a0 = 0, a1 = 0, a2 = 0, a3 = 0;
            int last = end - 1;
            for (int e = beg; e < end; e += 4) {
                int e1 = e + 1 > last ? last : e + 1;
                int e2 = e + 2 > last ? last : e + 2;
                int e3 = e + 3 > last ? last : e + 3;
                unsigned int s0 = (unsigned int)rsrc[e];
                unsigned int s1 = (unsigned int)rsrc[e1];
                unsigned int s2 = (unsigned int)rsrc[e2];
                unsigned int s3 = (unsigned int)rsrc[e3];
                float sv0 = *(const float*)(ss_b + (s0 * 16u + css));
                float sv1 = *(const float*)(ss_b + (s1 * 16u + css));
                float sv2 = *(const float*)(ss_b + (s2 * 16u + css));
                float sv3 = *(const float*)(ss_b + (s3 * 16u + css));
                ushort4 x0 = *(const ushort4*)(xpa_b + (s0 * 1536u + cxp));
                ushort4 x1 = *(const ushort4*)(xpa_b + (s1 * 1536u + cxp));
                ushort4 x2 = *(const ushort4*)(xpa_b + (s2 * 1536u + cxp));
                ushort4 x3 = *(const ushort4*)(xpa_b + (s3 * 1536u + cxp));
                // scores pre-scaled by log2e -> bare exp2
                float w0 = exp2f(lrelu_f(sv0 + sdh));
                float w1 = (e + 1 <= last) ? exp2f(lrelu_f(sv1 + sdh)) : 0.0f;
                float w2 = (e + 2 <= last) ? exp2f(lrelu_f(sv2 + sdh)) : 0.0f;
                float w3 = (e + 3 <= last) ? exp2f(lrelu_f(sv3 + sdh)) : 0.0f;
                den += (w0 + w1) + (w2 + w3);
                a0 += w0 * bf2f(x0.x) + w1 * bf2f(x1.x) + w2 * bf2f(x2.x) + w3 * bf2f(x3.x);
                a1 += w0 * bf2f(x0.y) + w1 * bf2f(x1.y) + w2 * bf2f(x2.y) + w3 * bf2f(x3.y);
                a2 += w0 * bf2f(x0.z) + w1 * bf2f(x1.z) + w2 * bf2f(x2.z) + w3 * bf2f(x3.z);
                a3 += w0 * bf2f(x0.w) + w1 * bf2f(x1.w) + w2 * bf2f(x2.w) + w3 * bf2f(x3.w);
            }
            float inv = 1.0f / (den + 1e-16f);
            agg0 += a0 * inv; agg1 += a1 * inv; agg2 += a2 * inv; agg3 += a3 * inv;
        }
        agg0 += bs0; agg1 += bs1; agg2 += bs2; agg3 += bs3;
        float part = agg0 * gwv.x + agg1 * gwv.y + agg2 * gwv.z + agg3 * gwv.w;
        if (lane < 4) part += liq[node * 4 + lane] * gwl;
        #pragma unroll
        for (int o = 32; o; o >>= 1) part += __shfl_xor(part, o);
        float gate = 1.0f / (1.0f + __expf(-(part + gb0)));
        float eg = ewg[node];
        ushort4 hu = *reinterpret_cast<const ushort4*>(&hb[(size_t)node * HID + lane * 4]);
        float h0 = bf2f(hu.x), h1 = bf2f(hu.y), h2 = bf2f(hu.z), h3 = bf2f(hu.w);
        float v0 = (gate * agg0 + (1.0f - gate) * h0) * eg + h0;
        float v1 = (gate * agg1 + (1.0f - gate) * h1) * eg + h1;
        float v2 = (gate * agg2 + (1.0f - gate) * h2) * eg + h2;
        float v3 = (gate * agg3 + (1.0f - gate) * h3) * eg + h3;
        float s = v0 + v1 + v2 + v3;
        float q = v0 * v0 + v1 * v1 + v2 * v2 + v3 * v3;
        #pragma unroll
        for (int o = 32; o; o >>= 1) { s += __shfl_xor(s, o); q += __shfl_xor(q, o); }
        float mean = s * (1.0f / HID);
        float var = q * (1.0f / HID) - mean * mean;
        float rs = rsqrtf(var + 1e-5f);
        float o0 = gelu_f(lgv.x * (v0 - mean) * rs + lbv.x);
        float o1 = gelu_f(lgv.y * (v1 - mean) * rs + lbv.y);
        float o2 = gelu_f(lgv.z * (v2 - mean) * rs + lbv.z);
        float o3 = gelu_f(lgv.w * (v3 - mean) * rs + lbv.w);
        float4 ov = {o0, o1, o2, o3};
        *reinterpret_cast<float4*>(&hout[(size_t)node * HID + lane * 4]) = ov;
        ushort4 ob;
        ob.x = f2bf(o0); ob.y = f2bf(o1); ob.z = f2bf(o2); ob.w = f2bf(o3);
        *reinterpret_cast<ushort4*>(&hb[(size_t)node * HID + lane * 4]) = ob;
    }
}

// ---------------- column partial sums of ho (N x D) ----------------
__global__ __launch_bounds__(128) void colpart_k(const float* __restrict__ ho,
                                                 float* __restrict__ part) {
    int c = threadIdx.x, b = blockIdx.x;
    float s = 0.0f;
    for (int r = b; r < NN; r += 256) s += ho[(size_t)r * DD + c];
    part[b * DD + c] = s;
}

// ---------------- readout MLP (single block) ----------------
__global__ __launch_bounds__(256) void readout_k(const float* __restrict__ part,
                                                 const float* __restrict__ W1,
                                                 const float* __restrict__ b1,
                                                 const float* __restrict__ W2,
                                                 const float* __restrict__ b2,
                                                 float* __restrict__ surf) {
    __shared__ float m[DD];
    __shared__ float a1[HID];
    int t = threadIdx.x;
    if (t < DD) {
        float s = 0.0f;
        for (int b = 0; b < 256; b++) s += part[b * DD + t];
        m[t] = s / (float)NN;
    }
    __syncthreads();
    float s1 = b1[t];
    for (int k = 0; k < DD; k++) s1 += m[k] * W1[k * HID + t];
    a1[t] = gelu_f(s1);
    __syncthreads();
    float s2 = b2[t];
    for (int k = 0; k < HID; k++) s2 += a1[k] * W2[k * HID + t];
    surf[t] = s2;
}

extern "C" void kernel_launch(void* const* d_in, const int* in_sizes, int n_in,
                              void* d_out, int out_size, void* d_ws, size_t ws_size,
                              hipStream_t stream) {
    const float* x       = (const float*)d_in[0];
    const float* liq     = (const float*)d_in[1];
    const int*   ei      = (const int*)d_in[2];
    const float* ew      = (const float*)d_in[3];
    const float* in_W    = (const float*)d_in[4];
    const float* in_b    = (const float*)d_in[5];
    const float* in_g    = (const float*)d_in[6];
    const float* in_bb   = (const float*)d_in[7];
    const float* gat_W   = (const float*)d_in[8];
    const float* gat_as  = (const float*)d_in[9];
    const float* gat_ad  = (const float*)d_in[10];
    const float* gat_b   = (const float*)d_in[11];
    const float* ln_g    = (const float*)d_in[12];
    const float* ln_b    = (const float*)d_in[13];
    const float* gate_W  = (const float*)d_in[14];
    const float* gate_b  = (const float*)d_in[15];
    const float* out_W1  = (const float*)d_in[16];
    const float* out_b1  = (const float*)d_in[17];
    const float* out_g   = (const float*)d_in[18];
    const float* out_bb  = (const float*)d_in[19];
    const float* out_W2  = (const float*)d_in[20];
    const float* out_b2  = (const float*)d_in[21];
    const float* ro_W1   = (const float*)d_in[22];
    const float* ro_b1   = (const float*)d_in[23];
    const float* ro_W2   = (const float*)d_in[24];
    const float* ro_b2   = (const float*)d_in[25];

    float* out = (float*)d_out;
    float* out_ho   = out;
    float* out_surf = out + (size_t)NN * DD;
    float* out_h[3];
    out_h[0] = out_surf + HID;
    out_h[1] = out_h[0] + (size_t)NN * HID;
    out_h[2] = out_h[1] + (size_t)NN * HID;

    char* wsb = (char*)d_ws;
    size_t off = 0;
    auto alloc = [&](size_t bytes) { char* p = wsb + off; off += (bytes + 255) & ~(size_t)255; return p; };
    // xpa bf16 [NN][768] (61.4 MB). Aliases inside it:
    //   ybf (bf16 GEMM out, NN*256 ushorts = 20.5 MB) at the front — live only in the
    //     input-proj and head-W1 phases; dead before layer GEMMs overwrite xpa.
    //   xb (bf16 x, NN*128 ushorts) at ushort offset NN*512 — dead after input GEMM.
    unsigned short* xpa = (unsigned short*)alloc((size_t)NN * NP * 2);
    unsigned short* ybf = xpa;
    unsigned short* xb = xpa + (size_t)NN * 512;
    unsigned short* hb = (unsigned short*)alloc((size_t)NN * HID * 2);  // bf16 h shadow
    unsigned short* Wt_in  = (unsigned short*)alloc((size_t)DD * HID * 2);
    unsigned short* Wt_gat = (unsigned short*)alloc((size_t)LL * NT * HID * HID * 2); // [L][768][256]
    unsigned short* Wt_o1  = (unsigned short*)alloc((size_t)HID * HID * 2);
    unsigned short* Wt_o2  = (unsigned short*)alloc((size_t)HID * DD * 2);
    size_t cew_b = (size_t)NT * EE * 4;
    size_t cnt_b = (size_t)NT * NN * 4;
    char* R = alloc(cew_b + cnt_b + 2 * 2048 * 4);
    float* cew = (float*)R;
    int* cnt   = (int*)(R + cew_b);
    int* bsum  = (int*)(R + cew_b + cnt_b);
    int* boff  = bsum + 2048;
    float* ss  = (float*)R;                  // alias: live only after ewg_kernel
    float* sd  = ss + (size_t)NT * NN * NH;
    int* roff  = (int*)alloc(((size_t)NT * NN + 1) * 4);
    int* rsrc  = (int*)alloc((size_t)NT * EE * 4);
    float* ewg = (float*)alloc((size_t)NN * 4);
    float* cpart = (float*)alloc((size_t)256 * DD * 4);

    const int NSC = (NT * NN + 255) / 256;

    // ---- weight conversions ----
    wconv_k<<<(DD * HID + 255) / 256, 256, 0, stream>>>(in_W, Wt_in, 1, DD, HID);
    wconv_k<<<(LL * NT * HID * HID + 255) / 256, 256, 0, stream>>>(gat_W, Wt_gat, LL * NT, HID, HID);
    wconv_k<<<(HID * HID + 255) / 256, 256, 0, stream>>>(out_W1, Wt_o1, 1, HID, HID);
    wconv_k<<<(HID * DD + 255) / 256, 256, 0, stream>>>(out_W2, Wt_o2, 1, HID, DD);
    xconv_k<<<(NN * DD / 4 + 255) / 256, 256, 0, stream>>>(x, xb);

    // ---- input projection + LN + GELU -> h0 (bf16 in hb) ----
    gemm_mfma_k<<<dim3(HID / 128, (NN + 127) / 128), 256, 0, stream>>>(
        xb, Wt_in, in_b, nullptr, ybf, nullptr, nullptr, nullptr, nullptr, NN, DD, HID);
    ln_gelu_bf_k<<<NN / 4, 256, 0, stream>>>(ybf, in_g, in_bb, hb);

    // ---- CSR build ----
    hipMemsetAsync(cnt, 0, cnt_b, stream);
    hist_k<<<(NT * EE + 255) / 256, 256, 0, stream>>>(ei, cnt);
    scan1_k<<<NSC, 256, 0, stream>>>(cnt, bsum, NT * NN);
    scan2_k<<<1, 512, 0, stream>>>(bsum, boff, NSC);
    scan3_k<<<NSC, 256, 0, stream>>>(cnt, boff, roff, NT * NN);
    hipMemsetAsync(cnt, 0, cnt_b, stream);
    scatter_k<<<(NT * EE + 255) / 256, 256, 0, stream>>>(ei, ew, roff, cnt, rsrc, cew);
    ewg_kernel<<<(NN + 255) / 256, 256, 0, stream>>>(roff, cew, ewg);

    // ---- message-passing layers (scores fused into GEMM epilogue) ----
    for (int i = 0; i < LL; i++) {
        gemm_mfma_k<<<dim3(NP / 128, (NN + 127) / 128), 256, 0, stream>>>(
            hb, Wt_gat + (size_t)i * NP * HID, nullptr, nullptr, xpa,
            gat_as + (size_t)i * NT * HID, gat_ad + (size_t)i * NT * HID, ss, sd,
            NN, HID, NP);
        layer_k<<<LGRID, 256, 0, stream>>>(
            xpa, ss, sd, roff, rsrc, gat_b + (size_t)i * NT * HID,
            liq, gate_W, gate_b, ewg, ln_g + i * HID, ln_b + i * HID,
            out_h[i], hb);
    }

    // ---- output head ----
    gemm_mfma_k<<<dim3(HID / 128, (NN + 127) / 128), 256, 0, stream>>>(
        hb, Wt_o1, out_b1, nullptr, ybf, nullptr, nullptr, nullptr, nullptr, NN, HID, HID);
    ln_gelu_bf_k<<<NN / 4, 256, 0, stream>>>(ybf, out_g, out_bb, hb);
    gemm_mfma_k<<<dim3(DD / 128, (NN + 127) / 128), 256, 0, stream>>>(
        hb, Wt_o2, out_b2, out_ho, nullptr, nullptr, nullptr, nullptr, nullptr, NN, HID, DD);

    // ---- readout ----
    colpart_k<<<256, 128, 0, stream>>>(out_ho, cpart);
    readout_k<<<1, 256, 0, stream>>>(cpart, ro_W1, ro_b1, ro_W2, ro_b2, out_surf);
}

// Round 12
// 796.593 us; speedup vs baseline: 1.0548x; 1.0548x over previous
//
#include <hip/hip_runtime.h>
#include <hip/hip_bf16.h>
#include <math.h>

#define NN 40000
#define EE 320000
#define NT 3
#define LL 3
#define DD 128
#define HID 256
#define NH 4
#define CC 64
#define NP 768   // NT*HID: batched projection width
#define LGRID 2048  // layer_k persistent blocks (8192 waves)

typedef __attribute__((ext_vector_type(8))) short short8;
typedef __attribute__((ext_vector_type(4))) float f32x4;

__device__ __forceinline__ float gelu_f(float x) {
    return 0.5f * x * (1.0f + erff(x * 0.70710678118654752440f));
}
__device__ __forceinline__ float lrelu_f(float x) {
    return x > 0.0f ? x : 0.2f * x;
}
__device__ __forceinline__ float bf2f(unsigned short u) {
    unsigned int x = ((unsigned int)u) << 16;
    float f;
    __builtin_memcpy(&f, &x, 4);
    return f;
}
__device__ __forceinline__ unsigned short f2bf(float f) {
    __hip_bfloat16 h = __float2bfloat16(f);
    unsigned short u;
    __builtin_memcpy(&u, &h, 2);
    return u;
}
__device__ __forceinline__ void gload16(const void* g, void* l) {
    __builtin_amdgcn_global_load_lds(
        (const __attribute__((address_space(1))) unsigned int*)g,
        (__attribute__((address_space(3))) unsigned int*)l, 16, 0, 0);
}

// ---------------- weight transpose + bf16 convert: W[m][K][N] -> Wt[m][N][K] ----------------
__global__ void wconv_k(const float* __restrict__ W, unsigned short* __restrict__ Wt,
                        int nmat, int K, int N) {
    int idx = blockIdx.x * 256 + threadIdx.x;
    int tot = nmat * K * N;
    if (idx >= tot) return;
    int m = idx / (K * N);
    int rem = idx - m * (K * N);
    int k = rem / N;
    int n = rem - k * N;
    Wt[(size_t)m * K * N + (size_t)n * K + k] = f2bf(W[idx]);
}

// ---------------- x fp32 -> bf16 ----------------
__global__ void xconv_k(const float* __restrict__ x, unsigned short* __restrict__ xb) {
    int idx = blockIdx.x * 256 + threadIdx.x;
    if (idx >= NN * DD / 4) return;
    float4 v = *reinterpret_cast<const float4*>(&x[(size_t)idx * 4]);
    ushort4 o;
    o.x = f2bf(v.x); o.y = f2bf(v.y); o.z = f2bf(v.z); o.w = f2bf(v.w);
    *reinterpret_cast<ushort4*>(&xb[(size_t)idx * 4]) = o;
}

// ---------------- MFMA bf16 GEMM: C[M][N] = A[M][K] @ Bt[N][K]^T (+bias) ----------------
// XCD-chunked bijective block swizzle (N-tile fastest within an XCD chunk).
__global__ __launch_bounds__(256) void gemm_mfma_k(const unsigned short* __restrict__ A,
                                                   const unsigned short* __restrict__ Bt,
                                                   const float* __restrict__ bias,
                                                   float* __restrict__ Cf,
                                                   unsigned short* __restrict__ Cb,
                                                   int M, int K, int N) {
    __shared__ __align__(16) short As[128 * 32];
    __shared__ __align__(16) short Bs[128 * 32];
    int gdx = gridDim.x;
    int nwg = gdx * gridDim.y;
    int f = blockIdx.y * gdx + blockIdx.x;
    int q8 = nwg >> 3, r8 = nwg & 7;
    int xcd = f & 7, idx8 = f >> 3;
    int nf = (xcd < r8 ? xcd * (q8 + 1) : r8 * (q8 + 1) + (xcd - r8) * q8) + idx8;
    int bn = (nf % gdx) * 128;
    int bm = (nf / gdx) * 128;
    int tid = threadIdx.x;
    int lane = tid & 63, w = tid >> 6;
    int wr = w >> 1, wc = w & 1;
    int l16 = lane & 15, kgrp = lane >> 4;
    f32x4 acc[4][4] = {};
    for (int k0 = 0; k0 < K; k0 += 32) {
        #pragma unroll
        for (int i = 0; i < 2; i++) {
            int chunk = (i * 4 + w) * 64 + lane;     // 0..511
            int row = chunk >> 2, kq = chunk & 3;
            int grow = bm + row; if (grow > M - 1) grow = M - 1;
            gload16(A + (size_t)grow * K + k0 + kq * 8, &As[(i * 4 + w) * 512]);
        }
        #pragma unroll
        for (int i = 0; i < 2; i++) {
            int chunk = (i * 4 + w) * 64 + lane;
            int row = chunk >> 2, kq = chunk & 3;
            gload16(Bt + (size_t)(bn + row) * K + k0 + kq * 8, &Bs[(i * 4 + w) * 512]);
        }
        __syncthreads();
        short8 af[4], bf[4];
        #pragma unroll
        for (int mi = 0; mi < 4; mi++) {
            int row = wr * 64 + mi * 16 + l16;
            af[mi] = *reinterpret_cast<const short8*>(&As[row * 32 + kgrp * 8]);
        }
        #pragma unroll
        for (int ni = 0; ni < 4; ni++) {
            int nrow = wc * 64 + ni * 16 + l16;
            bf[ni] = *reinterpret_cast<const short8*>(&Bs[nrow * 32 + kgrp * 8]);
        }
        #pragma unroll
        for (int mi = 0; mi < 4; mi++)
            #pragma unroll
            for (int ni = 0; ni < 4; ni++)
                acc[mi][ni] = __builtin_amdgcn_mfma_f32_16x16x32_bf16(af[mi], bf[ni], acc[mi][ni], 0, 0, 0);
        __syncthreads();
    }
    #pragma unroll
    for (int mi = 0; mi < 4; mi++) {
        #pragma unroll
        for (int r = 0; r < 4; r++) {
            int row = bm + wr * 64 + mi * 16 + (lane >> 4) * 4 + r;
            if (row < M) {
                #pragma unroll
                for (int ni = 0; ni < 4; ni++) {
                    int col = bn + wc * 64 + ni * 16 + l16;
                    float v = acc[mi][ni][r] + (bias ? bias[col] : 0.0f);
                    if (Cf) Cf[(size_t)row * N + col] = v;
                    if (Cb) Cb[(size_t)row * N + col] = f2bf(v);
                }
            }
        }
    }
}

// ---------------- LayerNorm + GELU, one wave per row of 256 ----------------
__global__ __launch_bounds__(256) void ln_gelu_k(const float* __restrict__ y,
                                                 const float* __restrict__ g,
                                                 const float* __restrict__ b,
                                                 float* __restrict__ outf,
                                                 unsigned short* __restrict__ outb) {
    int n = blockIdx.x * 4 + (threadIdx.x >> 6);
    int lane = threadIdx.x & 63;
    float4 v = *reinterpret_cast<const float4*>(&y[(size_t)n * HID + lane * 4]);
    float s = v.x + v.y + v.z + v.w;
    float q = v.x * v.x + v.y * v.y + v.z * v.z + v.w * v.w;
    #pragma unroll
    for (int o = 32; o; o >>= 1) { s += __shfl_xor(s, o); q += __shfl_xor(q, o); }
    float mean = s * (1.0f / HID);
    float var = q * (1.0f / HID) - mean * mean;
    float rs = rsqrtf(var + 1e-5f);
    float4 gv = *reinterpret_cast<const float4*>(&g[lane * 4]);
    float4 bv = *reinterpret_cast<const float4*>(&b[lane * 4]);
    float o0 = gelu_f(gv.x * (v.x - mean) * rs + bv.x);
    float o1 = gelu_f(gv.y * (v.y - mean) * rs + bv.y);
    float o2 = gelu_f(gv.z * (v.z - mean) * rs + bv.z);
    float o3 = gelu_f(gv.w * (v.w - mean) * rs + bv.w);
    if (outf) {
        float4 ov = {o0, o1, o2, o3};
        *reinterpret_cast<float4*>(&outf[(size_t)n * HID + lane * 4]) = ov;
    }
    ushort4 ob;
    ob.x = f2bf(o0); ob.y = f2bf(o1); ob.z = f2bf(o2); ob.w = f2bf(o3);
    *reinterpret_cast<ushort4*>(&outb[(size_t)n * HID + lane * 4]) = ob;
}

// ---------------- CSR build: batched over 3 edge types ----------------
__global__ void hist_k(const int* __restrict__ ei, int* __restrict__ cnt) {
    int gid = blockIdx.x * 256 + threadIdx.x;
    if (gid >= NT * EE) return;
    int t = gid / EE, e = gid - t * EE;
    int dst = ei[(size_t)t * 2 * EE + EE + e];
    atomicAdd(&cnt[t * NN + dst], 1);
}

__global__ __launch_bounds__(256) void scan1_k(const int* __restrict__ cnt, int* __restrict__ bsum, int n) {
    int i = blockIdx.x * 256 + threadIdx.x;
    int v = (i < n) ? cnt[i] : 0;
    #pragma unroll
    for (int o = 32; o; o >>= 1) v += __shfl_xor(v, o);
    __shared__ int s4[4];
    if ((threadIdx.x & 63) == 0) s4[threadIdx.x >> 6] = v;
    __syncthreads();
    if (threadIdx.x == 0) bsum[blockIdx.x] = s4[0] + s4[1] + s4[2] + s4[3];
}

__global__ __launch_bounds__(512) void scan2_k(const int* __restrict__ bsum, int* __restrict__ boff, int nb) {
    __shared__ int sh[512];
    int t = threadIdx.x;
    int v = (t < nb) ? bsum[t] : 0;
    sh[t] = v;
    __syncthreads();
    for (int o = 1; o < 512; o <<= 1) {
        int tv = (t >= o) ? sh[t - o] : 0;
        __syncthreads();
        sh[t] += tv;
        __syncthreads();
    }
    if (t < nb) boff[t] = sh[t] - v;
}

__global__ __launch_bounds__(256) void scan3_k(const int* __restrict__ cnt, const int* __restrict__ boff,
                                               int* __restrict__ roff, int n) {
    int i = blockIdx.x * 256 + threadIdx.x;
    int lane = threadIdx.x & 63, w = threadIdx.x >> 6;
    int v = (i < n) ? cnt[i] : 0;
    int s = v;
    #pragma unroll
    for (int o = 1; o < 64; o <<= 1) {
        int tv = __shfl_up(s, o);
        if (lane >= o) s += tv;
    }
    __shared__ int ws_[4];
    if (lane == 63) ws_[w] = s;
    __syncthreads();
    int add = 0;
    for (int k = 0; k < 4; k++) if (k < w) add += ws_[k];
    int incl = s + add + boff[blockIdx.x];
    if (i < n) roff[i] = incl - v;
    if (i == n - 1) roff[n] = incl;
}

__global__ void scatter_k(const int* __restrict__ ei, const float* __restrict__ ew,
                          const int* __restrict__ roff, int* __restrict__ cur,
                          int* __restrict__ csr_src, float* __restrict__ csr_ew) {
    int gid = blockIdx.x * 256 + threadIdx.x;
    if (gid >= NT * EE) return;
    int t = gid / EE, e = gid - t * EE;
    int src = ei[(size_t)t * 2 * EE + e];
    int dst = ei[(size_t)t * 2 * EE + EE + e];
    int pos = roff[t * NN + dst] + atomicAdd(&cur[t * NN + dst], 1);
    csr_src[pos] = src;
    csr_ew[pos] = ew[gid];
}

// ---------------- edge-weight gate from CSR ----------------
__global__ void ewg_kernel(const int* __restrict__ roff, const float* __restrict__ csr_ew,
                           float* __restrict__ ewg) {
    int n = blockIdx.x * 256 + threadIdx.x;
    if (n >= NN) return;
    float ws = 0.0f;
    int dg = 0;
    for (int t = 0; t < NT; t++) {
        int beg = roff[t * NN + n], end = roff[t * NN + n + 1];
        dg += end - beg;
        for (int e = beg; e < end; e++) ws += csr_ew[e];
    }
    float m = dg > 1 ? (float)dg : 1.0f;
    float z = ws / m;
    ewg[n] = 0.5f + 1.0f / (1.0f + __expf(-z));
}

// ---------------- per-(node,head) attention score inputs (bf16 xpa [NN][768]) -----
// Scores are pre-scaled by log2e (folded into a-vectors) so layer_k can use exp2.
__global__ __launch_bounds__(256) void compute_s_k(const unsigned short* __restrict__ xpa,
                                                   const float* __restrict__ asrc,  // [3][256]
                                                   const float* __restrict__ adst,
                                                   float* __restrict__ ss,          // [3][NN][4]
                                                   float* __restrict__ sd) {
    const float L2E = 1.4426950408889634f;
    int t = blockIdx.x / (NN / 4);
    int node = (blockIdx.x % (NN / 4)) * 4 + (threadIdx.x >> 6);
    int lane = threadIdx.x & 63;
    ushort4 v = *reinterpret_cast<const ushort4*>(&xpa[(size_t)node * NP + t * HID + lane * 4]);
    float4 av = *reinterpret_cast<const float4*>(&asrc[t * HID + lane * 4]);
    float4 dv = *reinterpret_cast<const float4*>(&adst[t * HID + lane * 4]);
    float x0 = bf2f(v.x), x1 = bf2f(v.y), x2 = bf2f(v.z), x3 = bf2f(v.w);
    float p = x0 * av.x + x1 * av.y + x2 * av.z + x3 * av.w;
    float q = x0 * dv.x + x1 * dv.y + x2 * dv.z + x3 * dv.w;
    #pragma unroll
    for (int o = 8; o; o >>= 1) { p += __shfl_xor(p, o); q += __shfl_xor(q, o); }
    if ((lane & 15) == 0) {
        ss[((size_t)t * NN + node) * NH + (lane >> 4)] = p * L2E;
        sd[((size_t)t * NN + node) * NH + (lane >> 4)] = q * L2E;
    }
}

// ---- fused layer: 3-type GAT agg (no-max softmax via exp2, chunk-4 gathers, 32-bit
//      voffsets) + gate + ewg + residual + LN + GELU. Persistent grid-stride waves.
__global__ __launch_bounds__(256) void layer_k(const unsigned short* __restrict__ xpa, // [NN][768]
                                               const float* __restrict__ ss,
                                               const float* __restrict__ sd,
                                               const int* __restrict__ roff,
                                               const int* __restrict__ rsrc,
                                               const float* __restrict__ gatb,  // [3][256]
                                               const float* __restrict__ liq,
                                               const float* __restrict__ gW,    // [260]
                                               const float* __restrict__ gb,    // [1]
                                               const float* __restrict__ ewg,
                                               const float* __restrict__ lg,
                                               const float* __restrict__ lb,
                                               float* __restrict__ hout,
                                               unsigned short* __restrict__ hb) { // in+out
    int wid = blockIdx.x * 4 + (threadIdx.x >> 6);
    int lane = threadIdx.x & 63;
    int h = lane >> 4;
    const int nw = LGRID * 4;
    const char* xpa_b = (const char*)xpa;
    const char* ss_b = (const char*)ss;
    float4 bb0 = *reinterpret_cast<const float4*>(&gatb[lane * 4]);
    float4 bb1 = *reinterpret_cast<const float4*>(&gatb[HID + lane * 4]);
    float4 bb2 = *reinterpret_cast<const float4*>(&gatb[2 * HID + lane * 4]);
    float bs0 = bb0.x + bb1.x + bb2.x;
    float bs1 = bb0.y + bb1.y + bb2.y;
    float bs2 = bb0.z + bb1.z + bb2.z;
    float bs3 = bb0.w + bb1.w + bb2.w;
    float4 gwv = *reinterpret_cast<const float4*>(&gW[lane * 4]);
    float gwl = (lane < 4) ? gW[HID + lane] : 0.0f;
    float gb0 = gb[0];
    float4 lgv = *reinterpret_cast<const float4*>(&lg[lane * 4]);
    float4 lbv = *reinterpret_cast<const float4*>(&lb[lane * 4]);

    for (int node = wid; node < NN; node += nw) {
        float agg0 = 0, agg1 = 0, agg2 = 0, agg3 = 0;
        #pragma unroll
        for (int t = 0; t < NT; t++) {
            int base = t * NN;
            int beg = roff[base + node], end = roff[base + node + 1];
            if (beg == end) continue;
            float sdh = sd[(size_t)(base + node) * NH + h];
            unsigned int cxp = (unsigned int)(t * 512 + lane * 8);       // byte off in xpa rows
            unsigned int css = (unsigned int)(t * NN * 16 + h * 4);      // byte off in ss
            float den = 0, a0 = 0, a1 = 0, a2 = 0, a3 = 0;
            int last = end - 1;
            for (int e = beg; e < end; e += 4) {
                int e1 = e + 1 > last ? last : e + 1;
                int e2 = e + 2 > last ? last : e + 2;
                int e3 = e + 3 > last ? last : e + 3;
                unsigned int s0 = (unsigned int)rsrc[e];
                unsigned int s1 = (unsigned int)rsrc[e1];
                unsigned int s2 = (unsigned int)rsrc[e2];
                unsigned int s3 = (unsigned int)rsrc[e3];
                float sv0 = *(const float*)(ss_b + (s0 * 16u + css));
                float sv1 = *(const float*)(ss_b + (s1 * 16u + css));
                float sv2 = *(const float*)(ss_b + (s2 * 16u + css));
                float sv3 = *(const float*)(ss_b + (s3 * 16u + css));
                ushort4 x0 = *(const ushort4*)(xpa_b + (s0 * 1536u + cxp));
                ushort4 x1 = *(const ushort4*)(xpa_b + (s1 * 1536u + cxp));
                ushort4 x2 = *(const ushort4*)(xpa_b + (s2 * 1536u + cxp));
                ushort4 x3 = *(const ushort4*)(xpa_b + (s3 * 1536u + cxp));
                // scores pre-scaled by log2e -> bare exp2
                float w0 = exp2f(lrelu_f(sv0 + sdh));
                float w1 = (e + 1 <= last) ? exp2f(lrelu_f(sv1 + sdh)) : 0.0f;
                float w2 = (e + 2 <= last) ? exp2f(lrelu_f(sv2 + sdh)) : 0.0f;
                float w3 = (e + 3 <= last) ? exp2f(lrelu_f(sv3 + sdh)) : 0.0f;
                den += (w0 + w1) + (w2 + w3);
                a0 += w0 * bf2f(x0.x) + w1 * bf2f(x1.x) + w2 * bf2f(x2.x) + w3 * bf2f(x3.x);
                a1 += w0 * bf2f(x0.y) + w1 * bf2f(x1.y) + w2 * bf2f(x2.y) + w3 * bf2f(x3.y);
                a2 += w0 * bf2f(x0.z) + w1 * bf2f(x1.z) + w2 * bf2f(x2.z) + w3 * bf2f(x3.z);
                a3 += w0 * bf2f(x0.w) + w1 * bf2f(x1.w) + w2 * bf2f(x2.w) + w3 * bf2f(x3.w);
            }
            float inv = 1.0f / (den + 1e-16f);
            agg0 += a0 * inv; agg1 += a1 * inv; agg2 += a2 * inv; agg3 += a3 * inv;
        }
        agg0 += bs0; agg1 += bs1; agg2 += bs2; agg3 += bs3;
        float part = agg0 * gwv.x + agg1 * gwv.y + agg2 * gwv.z + agg3 * gwv.w;
        if (lane < 4) part += liq[node * 4 + lane] * gwl;
        #pragma unroll
        for (int o = 32; o; o >>= 1) part += __shfl_xor(part, o);
        float gate = 1.0f / (1.0f + __expf(-(part + gb0)));
        float eg = ewg[node];
        ushort4 hu = *reinterpret_cast<const ushort4*>(&hb[(size_t)node * HID + lane * 4]);
        float h0 = bf2f(hu.x), h1 = bf2f(hu.y), h2 = bf2f(hu.z), h3 = bf2f(hu.w);
        float v0 = (gate * agg0 + (1.0f - gate) * h0) * eg + h0;
        float v1 = (gate * agg1 + (1.0f - gate) * h1) * eg + h1;
        float v2 = (gate * agg2 + (1.0f - gate) * h2) * eg + h2;
        float v3 = (gate * agg3 + (1.0f - gate) * h3) * eg + h3;
        float s = v0 + v1 + v2 + v3;
        float q = v0 * v0 + v1 * v1 + v2 * v2 + v3 * v3;
        #pragma unroll
        for (int o = 32; o; o >>= 1) { s += __shfl_xor(s, o); q += __shfl_xor(q, o); }
        float mean = s * (1.0f / HID);
        float var = q * (1.0f / HID) - mean * mean;
        float rs = rsqrtf(var + 1e-5f);
        float o0 = gelu_f(lgv.x * (v0 - mean) * rs + lbv.x);
        float o1 = gelu_f(lgv.y * (v1 - mean) * rs + lbv.y);
        float o2 = gelu_f(lgv.z * (v2 - mean) * rs + lbv.z);
        float o3 = gelu_f(lgv.w * (v3 - mean) * rs + lbv.w);
        float4 ov = {o0, o1, o2, o3};
        *reinterpret_cast<float4*>(&hout[(size_t)node * HID + lane * 4]) = ov;
        ushort4 ob;
        ob.x = f2bf(o0); ob.y = f2bf(o1); ob.z = f2bf(o2); ob.w = f2bf(o3);
        *reinterpret_cast<ushort4*>(&hb[(size_t)node * HID + lane * 4]) = ob;
    }
}

// ---------------- column partial sums of ho (N x D) ----------------
__global__ __launch_bounds__(128) void colpart_k(const float* __restrict__ ho,
                                                 float* __restrict__ part) {
    int c = threadIdx.x, b = blockIdx.x;
    float s = 0.0f;
    for (int r = b; r < NN; r += 256) s += ho[(size_t)r * DD + c];
    part[b * DD + c] = s;
}

// ---------------- readout MLP (single block) ----------------
__global__ __launch_bounds__(256) void readout_k(const float* __restrict__ part,
                                                 const float* __restrict__ W1,
                                                 const float* __restrict__ b1,
                                                 const float* __restrict__ W2,
                                                 const float* __restrict__ b2,
                                                 float* __restrict__ surf) {
    __shared__ float m[DD];
    __shared__ float a1[HID];
    int t = threadIdx.x;
    if (t < DD) {
        float s = 0.0f;
        for (int b = 0; b < 256; b++) s += part[b * DD + t];
        m[t] = s / (float)NN;
    }
    __syncthreads();
    float s1 = b1[t];
    for (int k = 0; k < DD; k++) s1 += m[k] * W1[k * HID + t];
    a1[t] = gelu_f(s1);
    __syncthreads();
    float s2 = b2[t];
    for (int k = 0; k < HID; k++) s2 += a1[k] * W2[k * HID + t];
    surf[t] = s2;
}

extern "C" void kernel_launch(void* const* d_in, const int* in_sizes, int n_in,
                              void* d_out, int out_size, void* d_ws, size_t ws_size,
                              hipStream_t stream) {
    const float* x       = (const float*)d_in[0];
    const float* liq     = (const float*)d_in[1];
    const int*   ei      = (const int*)d_in[2];
    const float* ew      = (const float*)d_in[3];
    const float* in_W    = (const float*)d_in[4];
    const float* in_b    = (const float*)d_in[5];
    const float* in_g    = (const float*)d_in[6];
    const float* in_bb   = (const float*)d_in[7];
    const float* gat_W   = (const float*)d_in[8];
    const float* gat_as  = (const float*)d_in[9];
    const float* gat_ad  = (const float*)d_in[10];
    const float* gat_b   = (const float*)d_in[11];
    const float* ln_g    = (const float*)d_in[12];
    const float* ln_b    = (const float*)d_in[13];
    const float* gate_W  = (const float*)d_in[14];
    const float* gate_b  = (const float*)d_in[15];
    const float* out_W1  = (const float*)d_in[16];
    const float* out_b1  = (const float*)d_in[17];
    const float* out_g   = (const float*)d_in[18];
    const float* out_bb  = (const float*)d_in[19];
    const float* out_W2  = (const float*)d_in[20];
    const float* out_b2  = (const float*)d_in[21];
    const float* ro_W1   = (const float*)d_in[22];
    const float* ro_b1   = (const float*)d_in[23];
    const float* ro_W2   = (const float*)d_in[24];
    const float* ro_b2   = (const float*)d_in[25];

    float* out = (float*)d_out;
    float* out_ho   = out;
    float* out_surf = out + (size_t)NN * DD;
    float* out_h[3];
    out_h[0] = out_surf + HID;
    out_h[1] = out_h[0] + (size_t)NN * HID;
    out_h[2] = out_h[1] + (size_t)NN * HID;

    char* wsb = (char*)d_ws;
    size_t off = 0;
    auto alloc = [&](size_t bytes) { char* p = wsb + off; off += (bytes + 255) & ~(size_t)255; return p; };
    // xpa bf16 [NN][768] (61.4 MB). Aliases inside it: Cf32 (fp32 GEMM out, 41 MB)
    // at the front; xb (bf16 x, 10.25 MB) after Cf32. Both dead before layer 0's GEMM.
    unsigned short* xpa = (unsigned short*)alloc((size_t)NN * NP * 2);
    float* Cf32 = (float*)xpa;
    unsigned short* xb = xpa + (size_t)NN * 512;
    unsigned short* hb = (unsigned short*)alloc((size_t)NN * HID * 2);  // bf16 h shadow
    unsigned short* Wt_in  = (unsigned short*)alloc((size_t)DD * HID * 2);
    unsigned short* Wt_gat = (unsigned short*)alloc((size_t)LL * NT * HID * HID * 2); // [L][768][256]
    unsigned short* Wt_o1  = (unsigned short*)alloc((size_t)HID * HID * 2);
    unsigned short* Wt_o2  = (unsigned short*)alloc((size_t)HID * DD * 2);
    size_t cew_b = (size_t)NT * EE * 4;
    size_t cnt_b = (size_t)NT * NN * 4;
    char* R = alloc(cew_b + cnt_b + 2 * 2048 * 4);
    float* cew = (float*)R;
    int* cnt   = (int*)(R + cew_b);
    int* bsum  = (int*)(R + cew_b + cnt_b);
    int* boff  = bsum + 2048;
    float* ss  = (float*)R;                  // alias: live only after ewg_kernel
    float* sd  = ss + (size_t)NT * NN * NH;
    int* roff  = (int*)alloc(((size_t)NT * NN + 1) * 4);
    int* rsrc  = (int*)alloc((size_t)NT * EE * 4);
    float* ewg = (float*)alloc((size_t)NN * 4);
    float* cpart = (float*)alloc((size_t)256 * DD * 4);

    const int NSC = (NT * NN + 255) / 256;

    // ---- weight conversions ----
    wconv_k<<<(DD * HID + 255) / 256, 256, 0, stream>>>(in_W, Wt_in, 1, DD, HID);
    wconv_k<<<(LL * NT * HID * HID + 255) / 256, 256, 0, stream>>>(gat_W, Wt_gat, LL * NT, HID, HID);
    wconv_k<<<(HID * HID + 255) / 256, 256, 0, stream>>>(out_W1, Wt_o1, 1, HID, HID);
    wconv_k<<<(HID * DD + 255) / 256, 256, 0, stream>>>(out_W2, Wt_o2, 1, HID, DD);
    xconv_k<<<(NN * DD / 4 + 255) / 256, 256, 0, stream>>>(x, xb);

    // ---- input projection + LN + GELU -> h0 (bf16 in hb) ----
    gemm_mfma_k<<<dim3(HID / 128, (NN + 127) / 128), 256, 0, stream>>>(
        xb, Wt_in, in_b, Cf32, nullptr, NN, DD, HID);
    ln_gelu_k<<<NN / 4, 256, 0, stream>>>(Cf32, in_g, in_bb, nullptr, hb);

    // ---- CSR build ----
    hipMemsetAsync(cnt, 0, cnt_b, stream);
    hist_k<<<(NT * EE + 255) / 256, 256, 0, stream>>>(ei, cnt);
    scan1_k<<<NSC, 256, 0, stream>>>(cnt, bsum, NT * NN);
    scan2_k<<<1, 512, 0, stream>>>(bsum, boff, NSC);
    scan3_k<<<NSC, 256, 0, stream>>>(cnt, boff, roff, NT * NN);
    hipMemsetAsync(cnt, 0, cnt_b, stream);
    scatter_k<<<(NT * EE + 255) / 256, 256, 0, stream>>>(ei, ew, roff, cnt, rsrc, cew);
    ewg_kernel<<<(NN + 255) / 256, 256, 0, stream>>>(roff, cew, ewg);

    // ---- message-passing layers ----
    for (int i = 0; i < LL; i++) {
        gemm_mfma_k<<<dim3(NP / 128, (NN + 127) / 128), 256, 0, stream>>>(
            hb, Wt_gat + (size_t)i * NP * HID, nullptr, nullptr, xpa, NN, HID, NP);
        compute_s_k<<<NT * (NN / 4), 256, 0, stream>>>(
            xpa, gat_as + (size_t)i * NT * HID, gat_ad + (size_t)i * NT * HID, ss, sd);
        layer_k<<<LGRID, 256, 0, stream>>>(
            xpa, ss, sd, roff, rsrc, gat_b + (size_t)i * NT * HID,
            liq, gate_W, gate_b, ewg, ln_g + i * HID, ln_b + i * HID,
            out_h[i], hb);
    }

    // ---- output head ----
    gemm_mfma_k<<<dim3(HID / 128, (NN + 127) / 128), 256, 0, stream>>>(
        hb, Wt_o1, out_b1, Cf32, nullptr, NN, HID, HID);
    ln_gelu_k<<<NN / 4, 256, 0, stream>>>(Cf32, out_g, out_bb, nullptr, hb);
    gemm_mfma_k<<<dim3(DD / 128, (NN + 127) / 128), 256, 0, stream>>>(
        hb, Wt_o2, out_b2, out_ho, nullptr, NN, HID, DD);

    // ---- readout ----
    colpart_k<<<256, 128, 0, stream>>>(out_ho, cpart);
    readout_k<<<1, 256, 0, stream>>>(cpart, ro_W1, ro_b1, ro_W2, ro_b2, out_surf);
}